// Round 3
// baseline (2376.010 us; speedup 1.0000x reference)
//
#include <hip/hip_runtime.h>
#include <cstdint>
#include <cstddef>
#include <math.h>

#define NANCH    36864
#define NPRE     12000
#define NPRE_PAD 12032
#define NW       188
#define SORT_N   16384
#define NPOST    2000

// triangle base for chunk-pair (ci, cj>=ci): slot = tribase(ci) + (cj-ci)
__device__ __forceinline__ int tribase(int ci) { return ci * NW - (ci * (ci - 1)) / 2; }
#define TRI_SLOTS (NW * (NW + 1) / 2)   // 17766

// ---------------------------------------------------------------------------
// K1: 3x3 conv (1024->512, 64x64, SAME) + bias + leaky_relu(0.01)
// f32 inputs, f64 accumulation (v_fma_f64): conv error ~1e-13 so score
// ranking matches a high-precision reference exactly (rois row-order hinges
// on argsort of scores; independent-f32 rounding rank-flips broke R2).
// ---------------------------------------------------------------------------
__global__ __launch_bounds__(256, 1)
void k_conv(const float* __restrict__ xg, const float* __restrict__ wg_,
            const float* __restrict__ bg, float* __restrict__ hg)
{
    __shared__ float wlds[144 * 64];     // [ic*9+k][oc]  36 KB
    __shared__ float xlds[16 * 4 * 76];  // [ic][srow][col] ~19 KB
    const int tid = threadIdx.x;
    const int oct = blockIdx.x & 7;
    const int rp  = blockIdx.x >> 3;     // 0..31 (row pairs)
    const int oc0 = oct << 6;
    const int y0  = rp << 1;
    const int ocg = tid >> 4;            // 0..15 -> 4 oc each
    const int pxg = tid & 15;
    const int ry  = pxg >> 3;            // 0/1 row within pair
    const int cx0 = (pxg & 7) << 3;      // 0..56 col base
    const int lane = tid & 63, wv = tid >> 6;

    double acc[4][8];
#pragma unroll
    for (int o = 0; o < 4; ++o)
#pragma unroll
        for (int j = 0; j < 8; ++j) acc[o][j] = 0.0;

    const float* wbase = wg_ + (size_t)(oc0 + lane) * 9216 + wv;
    float wreg[36], xreg[17];

    // prologue: load chunk 0 into registers
    {
#pragma unroll
        for (int t = 0; t < 36; ++t) wreg[t] = wbase[4 * t];
#pragma unroll
        for (int t = 0; t < 17; ++t) {
            int f = tid + 256 * t; float v = 0.f;
            if (f < 4224) {
                int ic = f / 264; int r = f - ic * 264; int srow = r / 66; int gc = r - srow * 66;
                int gy = y0 + srow - 1; int gx = gc - 1;
                if (gy >= 0 && gy < 64 && gx >= 0 && gx < 64)
                    v = xg[(size_t)ic * 4096 + gy * 64 + gx];
            }
            xreg[t] = v;
        }
    }

    for (int kc = 0; kc < 64; ++kc) {
        __syncthreads();
        // stage registers -> LDS
#pragma unroll
        for (int t = 0; t < 36; ++t) wlds[(wv + 4 * t) * 64 + lane] = wreg[t];
#pragma unroll
        for (int t = 0; t < 17; ++t) {
            int f = tid + 256 * t;
            if (f < 4224) {
                int ic = f / 264; int r = f - ic * 264; int srow = r / 66; int gc = r - srow * 66;
                xlds[(ic * 4 + srow) * 76 + gc] = xreg[t];
            }
        }
        // prefetch next chunk
        if (kc < 63) {
            const int ic0 = (kc + 1) << 4;
#pragma unroll
            for (int t = 0; t < 36; ++t) wreg[t] = wbase[ic0 * 9 + 4 * t];
#pragma unroll
            for (int t = 0; t < 17; ++t) {
                int f = tid + 256 * t; float v = 0.f;
                if (f < 4224) {
                    int ic = f / 264; int r = f - ic * 264; int srow = r / 66; int gc = r - srow * 66;
                    int gy = y0 + srow - 1; int gx = gc - 1;
                    if (gy >= 0 && gy < 64 && gx >= 0 && gx < 64)
                        v = xg[(size_t)(ic0 + ic) * 4096 + gy * 64 + gx];
                }
                xreg[t] = v;
            }
        }
        __syncthreads();
        // compute (f64 accumulate)
#pragma unroll 1
        for (int ic = 0; ic < 16; ++ic) {
#pragma unroll
            for (int ky = 0; ky < 3; ++ky) {
                const float* xr = &xlds[(ic * 4 + ry + ky) * 76 + cx0];
                float4 t0 = *(const float4*)(xr);
                float4 t1 = *(const float4*)(xr + 4);
                float2 t2 = *(const float2*)(xr + 8);
                double xwd[10] = {t0.x, t0.y, t0.z, t0.w, t1.x, t1.y, t1.z, t1.w, t2.x, t2.y};
#pragma unroll
                for (int kx = 0; kx < 3; ++kx) {
                    const float4 wq = *(const float4*)&wlds[(ic * 9 + ky * 3 + kx) * 64 + (ocg << 2)];
                    double wdv[4] = {wq.x, wq.y, wq.z, wq.w};
#pragma unroll
                    for (int o = 0; o < 4; ++o)
#pragma unroll
                        for (int j = 0; j < 8; ++j)
                            acc[o][j] = fma(wdv[o], xwd[j + kx], acc[o][j]);
                }
            }
        }
    }
    // epilogue: bias + leaky relu (f64), cast to f32, vectorized store
#pragma unroll
    for (int o = 0; o < 4; ++o) {
        const int oc = oc0 + (ocg << 2) + o;
        const double bo = (double)bg[oc];
        float* hp = hg + (size_t)oc * 4096 + (y0 + ry) * 64 + cx0;
        float v[8];
#pragma unroll
        for (int j = 0; j < 8; ++j) {
            double t = acc[o][j] + bo;
            v[j] = (float)((t >= 0.0) ? t : 0.01 * t);
        }
        *(float4*)(hp)     = make_float4(v[0], v[1], v[2], v[3]);
        *(float4*)(hp + 4) = make_float4(v[4], v[5], v[6], v[7]);
    }
}

// ---------------------------------------------------------------------------
// K2: 1x1 convs (f64 accumulate) + f64 sort keys + anchors + f32 box deparam
// 64 blocks (one per image row), 256 threads.
// Sort key: monotone bit-transform of f64 d=s1-s0, inverted (descending),
// top-48 bits | 16-bit anchor idx (36864 < 2^16) -> exact stable argsort.
// ---------------------------------------------------------------------------
__global__ __launch_bounds__(256, 1)
void k_heads(const float* __restrict__ hg, const float* __restrict__ loc_w,
             const float* __restrict__ loc_b, const float* __restrict__ score_w,
             const float* __restrict__ score_b, const int* __restrict__ imh,
             const int* __restrict__ imw, float* __restrict__ out,
             float* __restrict__ boxes_all, unsigned long long* __restrict__ keys64)
{
    __shared__ float  hch[64 * 64];   // [c][px] chunk of h
    __shared__ float  wch[54 * 64];   // [ch][c] chunk of weights
    __shared__ float  ol[54 * 64];    // [ch][px] f32 outputs
    __shared__ double sld[18 * 64];   // [score ch][px] f64 logits
    const int y = blockIdx.x, tid = threadIdx.x;
    const int px = tid & 63, cg = tid >> 6;
    double acc[14];
#pragma unroll
    for (int u = 0; u < 14; ++u) acc[u] = 0.0;

    for (int cc = 0; cc < 8; ++cc) {
        __syncthreads();
#pragma unroll
        for (int t = 0; t < 16; ++t) {
            int f = tid + 256 * t;
            hch[f] = hg[(size_t)(cc * 64 + (f >> 6)) * 4096 + y * 64 + (f & 63)];
        }
#pragma unroll
        for (int t = 0; t < 14; ++t) {
            int f = tid + 256 * t;
            if (f < 54 * 64) {
                int ch = f >> 6, c = f & 63;
                wch[f] = (ch < 36) ? loc_w[ch * 512 + cc * 64 + c]
                                   : score_w[(ch - 36) * 512 + cc * 64 + c];
            }
        }
        __syncthreads();
        for (int c = 0; c < 64; ++c) {
            double hvd = (double)hch[c * 64 + px];
#pragma unroll
            for (int u = 0; u < 14; ++u) {
                int ch = cg + 4 * u;
                if (ch < 54) acc[u] = fma((double)wch[ch * 64 + c], hvd, acc[u]);
            }
        }
    }
    __syncthreads();
#pragma unroll
    for (int u = 0; u < 14; ++u) {
        int ch = cg + 4 * u;
        if (ch < 54) {
            double s = acc[u] + (double)((ch < 36) ? loc_b[ch] : score_b[ch - 36]);
            ol[ch * 64 + px] = (float)s;
            if (ch >= 36) sld[(ch - 36) * 64 + px] = s;
        }
    }
    __syncthreads();
    // rpn_locs / rpn_scores outputs
    for (int f = tid; f < 64 * 36; f += 256) {
        int p = f / 36, ch = f - 36 * p;
        out[(size_t)(y * 64 + p) * 36 + ch] = ol[ch * 64 + p];
    }
    for (int f = tid; f < 64 * 18; f += 256) {
        int p = f / 18, ch = f - 18 * p;
        out[147456 + (size_t)(y * 64 + p) * 18 + ch] = ol[(36 + ch) * 64 + p];
    }
    const float fy = (float)(*imh), fx = (float)(*imw);
    float* anch = out + 229184;
    for (int t2 = tid; t2 < 576; t2 += 256) {
        int p = t2 / 9, a = t2 - 9 * p;
        int pg = y * 64 + p;
        int ar = a / 3, as = a - 3 * ar;
        double rr = (ar == 0) ? 0.5 : ((ar == 1) ? 1.0 : 2.0);
        double ss = (as == 0) ? 8.0 : ((as == 1) ? 16.0 : 32.0);
        double hh = 16.0 * ss * sqrt(rr), wwd = 16.0 * ss * sqrt(1.0 / rr);
        float by1 = (float)(8.0 - hh * 0.5), bx1 = (float)(8.0 - wwd * 0.5);
        float by2 = (float)(8.0 + hh * 0.5), bx2 = (float)(8.0 + wwd * 0.5);
        float sy = (float)(y * 16), sx = (float)(p * 16);
        float a0 = sy + by1, a1 = sx + bx1, a2 = sy + by2, a3 = sx + bx2;
        int base = (pg * 9 + a) * 4;
        anch[base + 0] = a0; anch[base + 1] = a1; anch[base + 2] = a2; anch[base + 3] = a3;
        // f64 sortable key from logit difference (monotone with fg)
        double d = sld[(a * 2 + 1) * 64 + p] - sld[(a * 2) * 64 + p];
        long long bits = __double_as_longlong(d);
        unsigned long long u64 =
            (unsigned long long)(bits ^ ((bits >> 63) | (long long)0x8000000000000000LL));
        unsigned long long v = ~u64;  // ascending v == descending d == descending fg
        keys64[pg * 9 + a] = (v & 0xFFFFFFFFFFFF0000ULL) | (unsigned long long)(pg * 9 + a);
        // deparam + clip (f32; elementwise exact-rounded ops)
        float dy = ol[(a * 4 + 0) * 64 + p], dxv = ol[(a * 4 + 1) * 64 + p];
        float dh = ol[(a * 4 + 2) * 64 + p], dwv = ol[(a * 4 + 3) * 64 + p];
        float hA = a2 - a0, wA = a3 - a1;
        float cya = a0 + 0.5f * hA, cxa = a1 + 0.5f * wA;
        float cy = dy * hA + cya, cx = dxv * wA + cxa;
        float hb = hA * expf(dh), wb = wA * expf(dwv);
        float b0 = fminf(fmaxf(cy - 0.5f * hb, 0.f), fy);
        float b1 = fminf(fmaxf(cx - 0.5f * wb, 0.f), fx);
        float b2 = fminf(fmaxf(cy + 0.5f * hb, 0.f), fy);
        float b3 = fminf(fmaxf(cx + 0.5f * wb, 0.f), fx);
        boxes_all[base + 0] = b0; boxes_all[base + 1] = b1;
        boxes_all[base + 2] = b2; boxes_all[base + 3] = b3;
    }
}

// ---------------------------------------------------------------------------
// K3: radix-select the 12000 SMALLEST keys (ascending key == descending score),
// compact, bitonic sort. Single block, 1024 threads, sortbuf in global ws.
// ---------------------------------------------------------------------------
__global__ __launch_bounds__(1024, 1)
void k_select(const unsigned long long* __restrict__ keys64,
              const float* __restrict__ boxes_all,
              unsigned long long* __restrict__ sortbuf, float* __restrict__ sbox,
              float* __restrict__ areas, unsigned long long* __restrict__ suppr)
{
    __shared__ unsigned int hist[256];
    __shared__ unsigned int sh_below, sh_prefix, sh_nsel;
    const int tid = threadIdx.x;
    if (tid == 0) { sh_below = 0; sh_prefix = 0; sh_nsel = 0; }
    __syncthreads();
    for (int p = 3; p >= 0; --p) {
        if (tid < 256) hist[tid] = 0;
        __syncthreads();
        unsigned int pref = sh_prefix;
        int shift = p * 8;
        for (int i = tid; i < NANCH; i += 1024) {
            unsigned int k = (unsigned int)(keys64[i] >> 32);
            bool match = (p == 3) || ((k >> (shift + 8)) == pref);
            if (match) atomicAdd(&hist[(k >> shift) & 255u], 1u);
        }
        __syncthreads();
        if (tid == 0) {
            unsigned int below = sh_below, cacc = 0;
            int b = 0;
            for (; b < 256; ++b) {
                if (below + cacc + hist[b] >= NPRE) break;
                cacc += hist[b];
            }
            if (b > 255) b = 255;
            sh_below = below + cacc;
            sh_prefix = (pref << 8) | (unsigned int)b;
        }
        __syncthreads();
    }
    const unsigned int P = sh_prefix;  // include all keys with high-32 <= P
    for (int i = tid; i < NANCH; i += 1024) {
        unsigned long long k = keys64[i];
        if ((unsigned int)(k >> 32) <= P) {
            unsigned int pos = atomicAdd(&sh_nsel, 1u);
            if (pos < SORT_N) sortbuf[pos] = k;
        }
    }
    __syncthreads();
    unsigned int nsel = sh_nsel; if (nsel > SORT_N) nsel = SORT_N;
    for (unsigned int i = nsel + tid; i < SORT_N; i += 1024) sortbuf[i] = ~0ULL;
    __syncthreads();
    // bitonic sort ascending; excess boundary ties sort past rank 12000
    for (int k2 = 2; k2 <= SORT_N; k2 <<= 1) {
        for (int j = k2 >> 1; j > 0; j >>= 1) {
            for (int t = tid; t < SORT_N / 2; t += 1024) {
                int i = ((t & ~(j - 1)) << 1) | (t & (j - 1));
                int ip = i | j;
                bool up = ((i & k2) == 0);
                unsigned long long A = sortbuf[i], B = sortbuf[ip];
                if ((A > B) == up) { sortbuf[i] = B; sortbuf[ip] = A; }
            }
            __syncthreads();
        }
    }
    if (tid < NW) suppr[tid] = (tid == NW - 1) ? 0xFFFFFFFF00000000ULL : 0ULL;
    __syncthreads();
    for (int r = tid; r < NPRE_PAD; r += 1024) {
        float b0 = 0, b1 = 0, b2 = 0, b3 = 0;
        if (r < NPRE) {
            unsigned int idx = (unsigned int)(sortbuf[r] & 0xFFFFULL);
            const float* bp = boxes_all + (size_t)idx * 4;
            b0 = bp[0]; b1 = bp[1]; b2 = bp[2]; b3 = bp[3];
        }
        sbox[r * 4 + 0] = b0; sbox[r * 4 + 1] = b1;
        sbox[r * 4 + 2] = b2; sbox[r * 4 + 3] = b3;
        areas[r] = (b2 - b0) * (b3 - b1);
        if (r < NPRE) {
            bool valid = ((b2 - b0) >= 16.0f) && ((b3 - b1) >= 16.0f);
            if (!valid) atomicOr(&suppr[r >> 6], 1ULL << (r & 63));
        }
    }
}

// ---------------------------------------------------------------------------
// K4: pairwise IoU bit mask, upper-triangle chunk-pair layout (9.1 MB).
// block (ci,cj), 64 threads; word t = bits of chunk cj suppressed by row
// ci*64+t (only j > i).
// ---------------------------------------------------------------------------
__global__ __launch_bounds__(64, 1)
void k_mask(const float* __restrict__ sbox, const float* __restrict__ areas,
            unsigned long long* __restrict__ mask)
{
    const int ci = blockIdx.x, cj = blockIdx.y;
    if (cj < ci) return;
    __shared__ float4 bx[64];
    __shared__ float aj[64];
    const int t = threadIdx.x;
    const int j0 = cj * 64;
    bx[t] = ((const float4*)sbox)[j0 + t];
    aj[t] = areas[j0 + t];
    __syncthreads();
    const int i = ci * 64 + t;
    const float4 p = ((const float4*)sbox)[i];
    const float ai = areas[i];
    unsigned long long w = 0;
    for (int jj = 0; jj < 64; ++jj) {
        float4 q = bx[jj];
        float yy1 = fmaxf(p.x, q.x), xx1 = fmaxf(p.y, q.y);
        float yy2 = fminf(p.z, q.z), xx2 = fminf(p.w, q.w);
        float inter = fmaxf(yy2 - yy1, 0.f) * fmaxf(xx2 - xx1, 0.f);
        float iou = inter / (ai + aj[jj] - inter + 1e-10f);
        w |= ((unsigned long long)((iou > 0.7f) && (j0 + jj > i))) << jj;
    }
    mask[(size_t)(tribase(ci) + (cj - ci)) * 64 + t] = w;
}

// ---------------------------------------------------------------------------
// K5: sequential greedy scan over 64-box chunks + rank + emit rois.
// ---------------------------------------------------------------------------
__global__ __launch_bounds__(256, 1)
void k_scan(const unsigned long long* __restrict__ mask,
            const unsigned long long* __restrict__ suppr,
            const float* __restrict__ sbox, float* __restrict__ rois)
{
    __shared__ unsigned long long curw;
    __shared__ unsigned long long keptw[NW];
    __shared__ int totkept, brk;
    __shared__ int pref[NW + 1];
    const int tid = threadIdx.x;
    unsigned long long rv = (tid < NW) ? suppr[tid] : ~0ULL;
    if (tid < NW) keptw[tid] = 0ULL;
    if (tid == 0) { totkept = 0; brk = 0; }
    __syncthreads();
    for (int c = 0; c < NW; ++c) {
        if (tid == c) curw = rv;
        __syncthreads();
        if (tid < 64) {  // wave-serial intra-chunk resolve (diag block of chunk c)
            unsigned long long diag = mask[(size_t)tribase(c) * 64 + tid];
            unsigned long long w = curw;
            for (int b = 0; b < 64; ++b) {
                unsigned long long db = __shfl(diag, b, 64);
                if (!((w >> b) & 1ULL)) w |= db;
            }
            if (tid == 0) curw = w;
        }
        __syncthreads();
        unsigned long long w = curw;
        if (tid == c) rv = w;
        unsigned long long kw = ~w;
        if (tid == 0) {
            keptw[c] = kw;
            totkept += __popcll(kw);
            if (totkept >= NPOST) brk = 1;
        }
        __syncthreads();
        if (brk) break;  // first 2000 kept decided; later chunks irrelevant
        if (tid > c && tid < NW) {  // apply kept rows of chunk c to future word tid
            const unsigned long long* mrow = mask + (size_t)(tribase(c) + (tid - c)) * 64;
            unsigned long long a0 = 0, a1 = 0, a2 = 0, a3 = 0;
            for (int b = 0; b < 64; b += 4) {
                unsigned long long m0 = mrow[b + 0];
                unsigned long long m1 = mrow[b + 1];
                unsigned long long m2 = mrow[b + 2];
                unsigned long long m3 = mrow[b + 3];
                if ((kw >> (b + 0)) & 1ULL) a0 |= m0;
                if ((kw >> (b + 1)) & 1ULL) a1 |= m1;
                if ((kw >> (b + 2)) & 1ULL) a2 |= m2;
                if ((kw >> (b + 3)) & 1ULL) a3 |= m3;
            }
            rv |= a0 | a1 | a2 | a3;
        }
        __syncthreads();
    }
    __syncthreads();
    if (tid == 0) {
        int s = 0;
        for (int c = 0; c < NW; ++c) { pref[c] = s; s += __popcll(keptw[c]); }
        pref[NW] = s;
    }
    __syncthreads();
    int total = pref[NW]; if (total > NPOST) total = NPOST;
    for (int r = total * 4 + tid; r < NPOST * 4; r += 256) rois[r] = 0.f;
    if (tid < NW) {
        unsigned long long kw = keptw[tid];
        int r = pref[tid];
        for (int b = 0; b < 64; ++b) {
            if ((kw >> b) & 1ULL) {
                if (r < NPOST) {
                    const float* bp = sbox + (size_t)(tid * 64 + b) * 4;
                    rois[r * 4 + 0] = bp[0]; rois[r * 4 + 1] = bp[1];
                    rois[r * 4 + 2] = bp[2]; rois[r * 4 + 3] = bp[3];
                }
                ++r;
            }
        }
    }
}

// ---------------------------------------------------------------------------
extern "C" void kernel_launch(void* const* d_in, const int* in_sizes, int n_in,
                              void* d_out, int out_size, void* d_ws, size_t ws_size,
                              hipStream_t stream)
{
    const float* x       = (const float*)d_in[0];
    const float* conv_w  = (const float*)d_in[1];
    const float* conv_b  = (const float*)d_in[2];
    const float* score_w = (const float*)d_in[3];
    const float* score_b = (const float*)d_in[4];
    const float* loc_w   = (const float*)d_in[5];
    const float* loc_b   = (const float*)d_in[6];
    const int*   imh     = (const int*)d_in[7];
    const int*   imw     = (const int*)d_in[8];
    float* out = (float*)d_out;
    char* ws = (char*)d_ws;
    // ws layout, total ~18.74 MB
    float* h                    = (float*)(ws);                         // 8388608
    float* boxes_all            = (float*)(ws + 8388608);               // 589824
    unsigned long long* keys64  = (unsigned long long*)(ws + 8978432);  // 294912
    float* sbox                 = (float*)(ws + 9273344);               // 192512
    float* areas                = (float*)(ws + 9465856);               // 48128
    unsigned long long* suppr   = (unsigned long long*)(ws + 9513984);  // 1536
    unsigned long long* sortbuf = (unsigned long long*)(ws + 9515520);  // 131072
    unsigned long long* mask    = (unsigned long long*)(ws + 9646592);  // 9096192

    k_conv  <<<256, 256, 0, stream>>>(x, conv_w, conv_b, h);
    k_heads <<<64, 256, 0, stream>>>(h, loc_w, loc_b, score_w, score_b, imh, imw,
                                     out, boxes_all, keys64);
    k_select<<<1, 1024, 0, stream>>>(keys64, boxes_all, sortbuf, sbox, areas, suppr);
    k_mask  <<<dim3(188, 188), 64, 0, stream>>>(sbox, areas, mask);
    k_scan  <<<1, 256, 0, stream>>>(mask, suppr, sbox, out + 221184);
}